// Round 4
// baseline (558.767 us; speedup 1.0000x reference)
//
#include <hip/hip_runtime.h>
#include <math.h>

#define N_WIRES 8
#define N_LAYERS 6
#define NG 49          // grid per axis (frequencies |n|<=24 -> 49 samples exact)
#define NG2 (NG * NG)  // 2401
#define FPAD 52        // padded row length for F (13 x float4)

// ws layout (bytes):
//   uv : [0,      3072)    48 gates x 16 floats
//   E  : [3072,   80000)   8 x 2401 floats (grid EVs, [i][a*49+b])
//   F  : [80128,  161664)  8 x 49 x FPAD floats (2D Fourier coeffs, padded)
#define WS_E_OFF 3072
#define WS_F_OFF 80128

// ---------------------------------------------------------------------------
// Per (layer, wire): U = RZ(w2)*RY(w1)*RX(w0) and V with fused gate
// G = c*U + s*V  ((c,s)=cos/sin(x0/2) even wires, (x1/2) odd wires).
// ---------------------------------------------------------------------------
__global__ void precompute_uv(const float* __restrict__ w, float* __restrict__ uv) {
    int t = threadIdx.x;
    if (t >= N_LAYERS * N_WIRES) return;
    int i = t & 7;
    float wx = w[t * 3 + 0], wy = w[t * 3 + 1], wz = w[t * 3 + 2];
    float sx, cx, sy, cy, sz, cz;
    sincosf(0.5f * wx, &sx, &cx);
    sincosf(0.5f * wy, &sy, &cy);
    sincosf(0.5f * wz, &sz, &cz);
    float A00r = cy * cx, A00i = sy * sx;
    float A01r = -sy * cx, A01i = -cy * sx;
    float A10r = sy * cx, A10i = -cy * sx;
    float A11r = cy * cx, A11i = -sy * sx;
    float U00r = A00r * cz + A00i * sz, U00i = A00i * cz - A00r * sz;
    float U01r = A01r * cz + A01i * sz, U01i = A01i * cz - A01r * sz;
    float U10r = A10r * cz - A10i * sz, U10i = A10i * cz + A10r * sz;
    float U11r = A11r * cz - A11i * sz, U11i = A11i * cz + A11r * sz;
    float V00r, V00i, V01r, V01i, V10r, V10i, V11r, V11i;
    if ((i & 1) == 0) {
        V00r = U01i; V00i = -U01r;
        V01r = U00i; V01i = -U00r;
        V10r = U11i; V10i = -U11r;
        V11r = U10i; V11i = -U10r;
    } else {
        V00r = U01r;  V00i = U01i;
        V01r = -U00r; V01i = -U00i;
        V10r = U11r;  V10i = U11i;
        V11r = -U10r; V11i = -U10i;
    }
    float* o = uv + t * 16;
    o[0] = U00r; o[1] = U00i; o[2] = U01r; o[3] = U01i;
    o[4] = U10r; o[5] = U10i; o[6] = U11r; o[7] = U11i;
    o[8] = V00r; o[9] = V00i; o[10] = V01r; o[11] = V01i;
    o[12] = V10r; o[13] = V10i; o[14] = V11r; o[15] = V11i;
}

// ---------------------------------------------------------------------------
// Grid circuit eval: one wave per grid point g=a*49+b ->
// (x0,x1)=(2*pi*a/49, 2*pi*b/49). Writes E[i][g].
// ---------------------------------------------------------------------------
__global__ __launch_bounds__(256) void qnn_grid_kernel(const float* __restrict__ uv,
                                                       float* __restrict__ E) {
    const int lane = threadIdx.x & 63;
    const int g = blockIdx.x * (blockDim.x >> 6) + (threadIdx.x >> 6);
    if (g >= NG2) return;

    const int ga = (g * 1338) >> 16;  // g/49, exact for g < 2404
    const int gb = g - ga * NG;
    const float step = (float)(2.0 * M_PI / 49.0);
    float x0 = step * (float)ga, x1 = step * (float)gb;
    float s0, c0, s1, c1;
    sincosf(0.5f * x0, &s0, &c0);
    sincosf(0.5f * x1, &s1, &c1);

    float ar[4] = {0.f, 0.f, 0.f, 0.f}, ai[4] = {0.f, 0.f, 0.f, 0.f};
    if (lane == 0) ar[0] = 1.0f;

    for (int l = 0; l < N_LAYERS; ++l) {
        const float* base = uv + l * 128;
        #pragma unroll
        for (int i = 0; i < 8; ++i) {
            const float* gm = base + i * 16;
            float ce = (i & 1) ? c1 : c0;
            float se = (i & 1) ? s1 : s0;
            float g00r = ce * gm[0] + se * gm[8],  g00i = ce * gm[1] + se * gm[9];
            float g01r = ce * gm[2] + se * gm[10], g01i = ce * gm[3] + se * gm[11];
            float g10r = ce * gm[4] + se * gm[12], g10i = ce * gm[5] + se * gm[13];
            float g11r = ce * gm[6] + se * gm[14], g11i = ce * gm[7] + se * gm[15];
            const int p = 7 - i;
            if (p >= 2) {
                const int m = 1 << (p - 2);
                const bool hi = (lane >> (p - 2)) & 1;
                float cor = hi ? g11r : g00r, coi = hi ? g11i : g00i;
                float cpr = hi ? g10r : g01r, cpi = hi ? g10i : g01i;
                #pragma unroll
                for (int j = 0; j < 4; ++j) {
                    float br = __shfl_xor(ar[j], m);
                    float bi = __shfl_xor(ai[j], m);
                    float nr = cor * ar[j] - coi * ai[j] + cpr * br - cpi * bi;
                    float ni = cor * ai[j] + coi * ar[j] + cpr * bi + cpi * br;
                    ar[j] = nr; ai[j] = ni;
                }
            } else {
                const int m = 1 << p;
                #pragma unroll
                for (int j0 = 0; j0 < 4; ++j0) {
                    if (j0 & m) continue;
                    const int j1 = j0 | m;
                    float a_r = ar[j0], a_i = ai[j0], b_r = ar[j1], b_i = ai[j1];
                    ar[j0] = g00r * a_r - g00i * a_i + g01r * b_r - g01i * b_i;
                    ai[j0] = g00r * a_i + g00i * a_r + g01r * b_i + g01i * b_r;
                    ar[j1] = g10r * a_r - g10i * a_i + g11r * b_r - g11i * b_i;
                    ai[j1] = g10r * a_i + g10i * a_r + g11r * b_i + g11i * b_r;
                }
            }
        }
        #pragma unroll
        for (int i = 0; i < 7; ++i) {
            const int pc = 7 - i, pt = 6 - i;
            if (pt >= 2) {
                const int m = 1 << (pt - 2);
                const bool ctrl = (lane >> (pc - 2)) & 1;
                #pragma unroll
                for (int j = 0; j < 4; ++j) {
                    float br = __shfl_xor(ar[j], m);
                    float bi = __shfl_xor(ai[j], m);
                    ar[j] = ctrl ? br : ar[j];
                    ai[j] = ctrl ? bi : ai[j];
                }
            } else if (pt == 1) {
                const bool ctrl = lane & 1;
                float n0r = ctrl ? ar[2] : ar[0], n0i = ctrl ? ai[2] : ai[0];
                float n2r = ctrl ? ar[0] : ar[2], n2i = ctrl ? ai[0] : ai[2];
                float n1r = ctrl ? ar[3] : ar[1], n1i = ctrl ? ai[3] : ai[1];
                float n3r = ctrl ? ar[1] : ar[3], n3i = ctrl ? ai[1] : ai[3];
                ar[0] = n0r; ai[0] = n0i; ar[1] = n1r; ai[1] = n1i;
                ar[2] = n2r; ai[2] = n2i; ar[3] = n3r; ai[3] = n3i;
            } else {
                float tr = ar[2], ti = ai[2];
                ar[2] = ar[3]; ai[2] = ai[3];
                ar[3] = tr;    ai[3] = ti;
            }
        }
    }

    float p0 = ar[0] * ar[0] + ai[0] * ai[0];
    float p1 = ar[1] * ar[1] + ai[1] * ai[1];
    float p2 = ar[2] * ar[2] + ai[2] * ai[2];
    float p3 = ar[3] * ar[3] + ai[3] * ai[3];
    float sAll = p0 + p1 + p2 + p3;

    float ev[8];
    #pragma unroll
    for (int i = 0; i < 6; ++i) ev[i] = ((lane >> (5 - i)) & 1) ? -sAll : sAll;
    ev[6] = p0 + p1 - p2 - p3;
    ev[7] = p0 - p1 + p2 - p3;

    #pragma unroll
    for (int i = 0; i < 8; ++i) {
        #pragma unroll
        for (int s = 1; s < 64; s <<= 1) ev[i] += __shfl_xor(ev[i], s);
    }

    if (lane == 0) {
        #pragma unroll
        for (int i = 0; i < 8; ++i) E[i * NG2 + g] = ev[i];
    }
}

// ---------------------------------------------------------------------------
// Fused 2D DFT: one block per output i. E[i] -> LDS, G = E*T_b in LDS,
// F[i] = T_a^T * G to global (rows padded to FPAD, pad zeroed).
// T[b][0]=1/49; T[b][2n-1]=(2/49)cos(2pi n b/49); T[b][2n]=(2/49)sin(...).
// ---------------------------------------------------------------------------
__global__ __launch_bounds__(256) void dft_fused(const float* __restrict__ E,
                                                 float* __restrict__ F) {
    __shared__ float Es[NG2];
    __shared__ float Gs[NG2];
    const int i = blockIdx.x, t = threadIdx.x;

    for (int e = t; e < NG2; e += 256) Es[e] = E[i * NG2 + e];
    __syncthreads();

    // G[a][k] = sum_b Es[a*49+b] * T[b][k]
    for (int e = t; e < NG2; e += 256) {
        const int a = (e * 1338) >> 16;
        const int k = e - a * NG;
        const float* Er = Es + a * NG;
        float acc = 0.f;
        if (k == 0) {
            for (int b = 0; b < NG; ++b) acc += Er[b];
            acc *= (1.0f / 49.0f);
        } else {
            int n = (k + 1) >> 1;
            float cs, ss;
            sincosf((float)(2.0 * M_PI / 49.0) * (float)n, &ss, &cs);
            float cb = 1.f, sb = 0.f;
            const bool use_cos = (k & 1);
            for (int b = 0; b < NG; ++b) {
                acc = fmaf(Er[b], use_cos ? cb : sb, acc);
                float cn = cb * cs - sb * ss;
                float sn = sb * cs + cb * ss;
                cb = cn; sb = sn;
            }
            acc *= (2.0f / 49.0f);
        }
        Gs[e] = acc;
    }
    __syncthreads();

    // F[i][kp][l] = sum_a T[a][kp] * Gs[a*49+l]; write pad zeros for l>=49
    for (int e = t; e < NG * FPAD; e += 256) {
        const int kp = e / FPAD;
        const int l = e - kp * FPAD;
        float acc = 0.f;
        if (l < NG) {
            if (kp == 0) {
                for (int a = 0; a < NG; ++a) acc += Gs[a * NG + l];
                acc *= (1.0f / 49.0f);
            } else {
                int n = (kp + 1) >> 1;
                float cs, ss;
                sincosf((float)(2.0 * M_PI / 49.0) * (float)n, &ss, &cs);
                float ca = 1.f, sa = 0.f;
                const bool use_cos = (kp & 1);
                for (int a = 0; a < NG; ++a) {
                    acc = fmaf(Gs[a * NG + l], use_cos ? ca : sa, acc);
                    float cn = ca * cs - sa * ss;
                    float sn = sa * cs + ca * ss;
                    ca = cn; sa = sn;
                }
                acc *= (2.0f / 49.0f);
            }
        }
        F[(i * NG + kp) * FPAD + l] = acc;
    }
}

// ---------------------------------------------------------------------------
// Final contraction: out[b][i] = pi * v0(x0)^T F_i v1(x1).
// grid (B/256, 2, 2): y -> 4 outputs, z -> frequency half (n-split).
// z=0: row 0 + n=1..12 ; z=1: n=13..24. Partials combined via atomicAdd
// (out pre-zeroed with hipMemsetAsync). Doubles waves/SIMD (4 -> 8) without
// increasing aggregate F scalar traffic: each wave streams a disjoint half.
// ---------------------------------------------------------------------------
__device__ __forceinline__ float dot52(const float* __restrict__ r, const float (&v)[FPAD]) {
    float t0 = 0.f, t1 = 0.f, t2 = 0.f, t3 = 0.f;
    #pragma unroll
    for (int l = 0; l < FPAD; l += 4) {
        t0 = fmaf(r[l + 0], v[l + 0], t0);
        t1 = fmaf(r[l + 1], v[l + 1], t1);
        t2 = fmaf(r[l + 2], v[l + 2], t2);
        t3 = fmaf(r[l + 3], v[l + 3], t3);
    }
    return (t0 + t1) + (t2 + t3);
}

__global__ __launch_bounds__(256) void contract_kernel(const float* __restrict__ x,
                                                       const float* __restrict__ F,
                                                       float* __restrict__ out, int B) {
    const int b = blockIdx.x * 256 + threadIdx.x;
    const int i0 = blockIdx.y * 4;
    const int z = blockIdx.z;
    if (b >= B) return;

    float2 xv = ((const float2*)x)[b];
    float s0, c0, s1, c1;
    sincosf(xv.x, &s0, &c0);
    sincosf(xv.y, &s1, &c1);

    float v1[FPAD];
    v1[0] = 1.0f; v1[1] = c1; v1[2] = s1;
    #pragma unroll
    for (int n = 2; n <= 24; ++n) {
        v1[2 * n - 1] = v1[2 * n - 3] * c1 - v1[2 * n - 2] * s1;
        v1[2 * n]     = v1[2 * n - 2] * c1 + v1[2 * n - 3] * s1;
    }
    v1[49] = 0.f; v1[50] = 0.f; v1[51] = 0.f;

    const float* base = F + (size_t)i0 * NG * FPAD;
    float acc[4] = {0.f, 0.f, 0.f, 0.f};
    float Ck, Sk;
    const float* rp;
    if (z == 0) {
        #pragma unroll
        for (int i = 0; i < 4; ++i) acc[i] = dot52(base + i * NG * FPAD, v1);  // n=0 row
        Ck = c0; Sk = s0;            // start at n=1
        rp = base + 1 * FPAD;        // rows 1..24
    } else {
        sincosf(13.0f * xv.x, &Sk, &Ck);  // start at n=13
        rp = base + 25 * FPAD;            // rows 25..48
    }

    #pragma unroll 2
    for (int t = 0; t < 12; ++t) {
        #pragma unroll
        for (int i = 0; i < 4; ++i) {
            float tC = dot52(rp + i * NG * FPAD, v1);
            float tS = dot52(rp + i * NG * FPAD + FPAD, v1);
            acc[i] = fmaf(Ck, tC, acc[i]);
            acc[i] = fmaf(Sk, tS, acc[i]);
        }
        float Cn = Ck * c0 - Sk * s0;
        float Sn = Sk * c0 + Ck * s0;
        Ck = Cn; Sk = Sn;
        rp += 2 * FPAD;
    }

    const float PI = 3.14159265358979323846f;
    float* o = out + (size_t)b * 8 + i0;
    #pragma unroll
    for (int i = 0; i < 4; ++i) atomicAdd(o + i, PI * acc[i]);
}

extern "C" void kernel_launch(void* const* d_in, const int* in_sizes, int n_in,
                              void* d_out, int out_size, void* d_ws, size_t ws_size,
                              hipStream_t stream) {
    (void)n_in; (void)ws_size;
    const float* x = (const float*)d_in[0];
    const float* w = (const float*)d_in[1];
    float* out = (float*)d_out;
    char* ws = (char*)d_ws;
    float* uv = (float*)(ws);
    float* E  = (float*)(ws + WS_E_OFF);
    float* F  = (float*)(ws + WS_F_OFF);
    const int B = in_sizes[0] / 2;

    hipMemsetAsync(out, 0, (size_t)out_size * sizeof(float), stream);

    hipLaunchKernelGGL(precompute_uv, dim3(1), dim3(64), 0, stream, w, uv);
    hipLaunchKernelGGL(qnn_grid_kernel, dim3((NG2 + 3) / 4), dim3(256), 0, stream, uv, E);
    hipLaunchKernelGGL(dft_fused, dim3(8), dim3(256), 0, stream, E, F);
    hipLaunchKernelGGL(contract_kernel, dim3((B + 255) / 256, 2, 2), dim3(256), 0, stream,
                       x, F, out, B);
}

// Round 5
// 179.483 us; speedup vs baseline: 3.1132x; 3.1132x over previous
//
#include <hip/hip_runtime.h>
#include <math.h>

#define N_WIRES 8
#define N_LAYERS 6
#define NG 49          // grid per axis (frequencies |n|<=24 -> 49 samples exact)
#define NG2 (NG * NG)  // 2401
#define FPAD 52        // padded row length for F (13 x float4)

// ws layout (bytes):
//   E  : [0,      76832)   8 x 2401 floats (grid EVs, [i][a*49+b])
//   F  : [76832,  158368)  8 x 49 x FPAD floats (2D Fourier coeffs, padded)
#define WS_E_OFF 0
#define WS_F_OFF 76832

// ---------------------------------------------------------------------------
// Device helper: per (layer,wire) fused-gate tables U,V with
// G = c*U + s*V  ((c,s)=cos/sin(x0/2) even wires, (x1/2) odd wires).
// Computed per-block into LDS (48 threads, trivial cost) to save a launch.
// ---------------------------------------------------------------------------
__device__ __forceinline__ void compute_uv_lds(const float* __restrict__ w, float* uv, int t) {
    if (t >= N_LAYERS * N_WIRES) return;
    int i = t & 7;
    float wx = w[t * 3 + 0], wy = w[t * 3 + 1], wz = w[t * 3 + 2];
    float sx, cx, sy, cy, sz, cz;
    sincosf(0.5f * wx, &sx, &cx);
    sincosf(0.5f * wy, &sy, &cy);
    sincosf(0.5f * wz, &sz, &cz);
    float A00r = cy * cx, A00i = sy * sx;
    float A01r = -sy * cx, A01i = -cy * sx;
    float A10r = sy * cx, A10i = -cy * sx;
    float A11r = cy * cx, A11i = -sy * sx;
    float U00r = A00r * cz + A00i * sz, U00i = A00i * cz - A00r * sz;
    float U01r = A01r * cz + A01i * sz, U01i = A01i * cz - A01r * sz;
    float U10r = A10r * cz - A10i * sz, U10i = A10i * cz + A10r * sz;
    float U11r = A11r * cz - A11i * sz, U11i = A11i * cz + A11r * sz;
    float V00r, V00i, V01r, V01i, V10r, V10i, V11r, V11i;
    if ((i & 1) == 0) {
        V00r = U01i; V00i = -U01r;
        V01r = U00i; V01i = -U00r;
        V10r = U11i; V10i = -U11r;
        V11r = U10i; V11i = -U10r;
    } else {
        V00r = U01r;  V00i = U01i;
        V01r = -U00r; V01i = -U00i;
        V10r = U11r;  V10i = U11i;
        V11r = -U10r; V11i = -U10i;
    }
    float* o = uv + t * 16;
    o[0] = U00r; o[1] = U00i; o[2] = U01r; o[3] = U01i;
    o[4] = U10r; o[5] = U10i; o[6] = U11r; o[7] = U11i;
    o[8] = V00r; o[9] = V00i; o[10] = V01r; o[11] = V01i;
    o[12] = V10r; o[13] = V10i; o[14] = V11r; o[15] = V11i;
}

// ---------------------------------------------------------------------------
// Grid circuit eval: one wave per grid point g=a*49+b ->
// (x0,x1)=(2*pi*a/49, 2*pi*b/49). Writes E[i][g].
// ---------------------------------------------------------------------------
__global__ __launch_bounds__(256) void qnn_grid_kernel(const float* __restrict__ w,
                                                       float* __restrict__ E) {
    __shared__ float uv[N_LAYERS * N_WIRES * 16];
    compute_uv_lds(w, uv, threadIdx.x);
    __syncthreads();

    const int lane = threadIdx.x & 63;
    const int g = blockIdx.x * (blockDim.x >> 6) + (threadIdx.x >> 6);
    if (g >= NG2) return;

    const int ga = (g * 1338) >> 16;  // g/49, exact for g < 2404
    const int gb = g - ga * NG;
    const float step = (float)(2.0 * M_PI / 49.0);
    float x0 = step * (float)ga, x1 = step * (float)gb;
    float s0, c0, s1, c1;
    sincosf(0.5f * x0, &s0, &c0);
    sincosf(0.5f * x1, &s1, &c1);

    float ar[4] = {0.f, 0.f, 0.f, 0.f}, ai[4] = {0.f, 0.f, 0.f, 0.f};
    if (lane == 0) ar[0] = 1.0f;

    for (int l = 0; l < N_LAYERS; ++l) {
        const float* base = uv + l * 128;
        #pragma unroll
        for (int i = 0; i < 8; ++i) {
            const float* gm = base + i * 16;
            float ce = (i & 1) ? c1 : c0;
            float se = (i & 1) ? s1 : s0;
            float g00r = ce * gm[0] + se * gm[8],  g00i = ce * gm[1] + se * gm[9];
            float g01r = ce * gm[2] + se * gm[10], g01i = ce * gm[3] + se * gm[11];
            float g10r = ce * gm[4] + se * gm[12], g10i = ce * gm[5] + se * gm[13];
            float g11r = ce * gm[6] + se * gm[14], g11i = ce * gm[7] + se * gm[15];
            const int p = 7 - i;
            if (p >= 2) {
                const int m = 1 << (p - 2);
                const bool hi = (lane >> (p - 2)) & 1;
                float cor = hi ? g11r : g00r, coi = hi ? g11i : g00i;
                float cpr = hi ? g10r : g01r, cpi = hi ? g10i : g01i;
                #pragma unroll
                for (int j = 0; j < 4; ++j) {
                    float br = __shfl_xor(ar[j], m);
                    float bi = __shfl_xor(ai[j], m);
                    float nr = cor * ar[j] - coi * ai[j] + cpr * br - cpi * bi;
                    float ni = cor * ai[j] + coi * ar[j] + cpr * bi + cpi * br;
                    ar[j] = nr; ai[j] = ni;
                }
            } else {
                const int m = 1 << p;
                #pragma unroll
                for (int j0 = 0; j0 < 4; ++j0) {
                    if (j0 & m) continue;
                    const int j1 = j0 | m;
                    float a_r = ar[j0], a_i = ai[j0], b_r = ar[j1], b_i = ai[j1];
                    ar[j0] = g00r * a_r - g00i * a_i + g01r * b_r - g01i * b_i;
                    ai[j0] = g00r * a_i + g00i * a_r + g01r * b_i + g01i * b_r;
                    ar[j1] = g10r * a_r - g10i * a_i + g11r * b_r - g11i * b_i;
                    ai[j1] = g10r * a_i + g10i * a_r + g11r * b_i + g11i * b_r;
                }
            }
        }
        #pragma unroll
        for (int i = 0; i < 7; ++i) {
            const int pc = 7 - i, pt = 6 - i;
            if (pt >= 2) {
                const int m = 1 << (pt - 2);
                const bool ctrl = (lane >> (pc - 2)) & 1;
                #pragma unroll
                for (int j = 0; j < 4; ++j) {
                    float br = __shfl_xor(ar[j], m);
                    float bi = __shfl_xor(ai[j], m);
                    ar[j] = ctrl ? br : ar[j];
                    ai[j] = ctrl ? bi : ai[j];
                }
            } else if (pt == 1) {
                const bool ctrl = lane & 1;
                float n0r = ctrl ? ar[2] : ar[0], n0i = ctrl ? ai[2] : ai[0];
                float n2r = ctrl ? ar[0] : ar[2], n2i = ctrl ? ai[0] : ai[2];
                float n1r = ctrl ? ar[3] : ar[1], n1i = ctrl ? ai[3] : ai[1];
                float n3r = ctrl ? ar[1] : ar[3], n3i = ctrl ? ai[1] : ai[3];
                ar[0] = n0r; ai[0] = n0i; ar[1] = n1r; ai[1] = n1i;
                ar[2] = n2r; ai[2] = n2i; ar[3] = n3r; ai[3] = n3i;
            } else {
                float tr = ar[2], ti = ai[2];
                ar[2] = ar[3]; ai[2] = ai[3];
                ar[3] = tr;    ai[3] = ti;
            }
        }
    }

    float p0 = ar[0] * ar[0] + ai[0] * ai[0];
    float p1 = ar[1] * ar[1] + ai[1] * ai[1];
    float p2 = ar[2] * ar[2] + ai[2] * ai[2];
    float p3 = ar[3] * ar[3] + ai[3] * ai[3];
    float sAll = p0 + p1 + p2 + p3;

    float ev[8];
    #pragma unroll
    for (int i = 0; i < 6; ++i) ev[i] = ((lane >> (5 - i)) & 1) ? -sAll : sAll;
    ev[6] = p0 + p1 - p2 - p3;
    ev[7] = p0 - p1 + p2 - p3;

    #pragma unroll
    for (int i = 0; i < 8; ++i) {
        #pragma unroll
        for (int s = 1; s < 64; s <<= 1) ev[i] += __shfl_xor(ev[i], s);
    }

    if (lane == 0) {
        #pragma unroll
        for (int i = 0; i < 8; ++i) E[i * NG2 + g] = ev[i];
    }
}

// ---------------------------------------------------------------------------
// Fused 2D DFT: one block per output i. E[i] -> LDS, G = E*T_b in LDS,
// F[i] = T_a^T * G to global (rows padded to FPAD, pad zeroed).
// T[b][0]=1/49; T[b][2n-1]=(2/49)cos(2pi n b/49); T[b][2n]=(2/49)sin(...).
// ---------------------------------------------------------------------------
__global__ __launch_bounds__(256) void dft_fused(const float* __restrict__ E,
                                                 float* __restrict__ F) {
    __shared__ float Es[NG2];
    __shared__ float Gs[NG2];
    const int i = blockIdx.x, t = threadIdx.x;

    for (int e = t; e < NG2; e += 256) Es[e] = E[i * NG2 + e];
    __syncthreads();

    for (int e = t; e < NG2; e += 256) {
        const int a = (e * 1338) >> 16;
        const int k = e - a * NG;
        const float* Er = Es + a * NG;
        float acc = 0.f;
        if (k == 0) {
            for (int b = 0; b < NG; ++b) acc += Er[b];
            acc *= (1.0f / 49.0f);
        } else {
            int n = (k + 1) >> 1;
            float cs, ss;
            sincosf((float)(2.0 * M_PI / 49.0) * (float)n, &ss, &cs);
            float cb = 1.f, sb = 0.f;
            const bool use_cos = (k & 1);
            for (int b = 0; b < NG; ++b) {
                acc = fmaf(Er[b], use_cos ? cb : sb, acc);
                float cn = cb * cs - sb * ss;
                float sn = sb * cs + cb * ss;
                cb = cn; sb = sn;
            }
            acc *= (2.0f / 49.0f);
        }
        Gs[e] = acc;
    }
    __syncthreads();

    for (int e = t; e < NG * FPAD; e += 256) {
        const int kp = e / FPAD;
        const int l = e - kp * FPAD;
        float acc = 0.f;
        if (l < NG) {
            if (kp == 0) {
                for (int a = 0; a < NG; ++a) acc += Gs[a * NG + l];
                acc *= (1.0f / 49.0f);
            } else {
                int n = (kp + 1) >> 1;
                float cs, ss;
                sincosf((float)(2.0 * M_PI / 49.0) * (float)n, &ss, &cs);
                float ca = 1.f, sa = 0.f;
                const bool use_cos = (kp & 1);
                for (int a = 0; a < NG; ++a) {
                    acc = fmaf(Gs[a * NG + l], use_cos ? ca : sa, acc);
                    float cn = ca * cs - sa * ss;
                    float sn = sa * cs + ca * ss;
                    ca = cn; sa = sn;
                }
                acc *= (2.0f / 49.0f);
            }
        }
        F[(i * NG + kp) * FPAD + l] = acc;
    }
}

// ---------------------------------------------------------------------------
// Final contraction: out[b][i] = pi * v0(x0)^T F_i v1(x1).
// grid (B/256, 8): y = output index i — one output per thread. This gives
// 16384 waves (16/SIMD wanted) vs round-3's 4096 (grid-limited, VALUBusy 46%).
// Each wave streams only F_i (10.2 KB, wave-uniform -> scalar loads, L2-hot).
// Plain scalar store, no atomics.
// ---------------------------------------------------------------------------
__device__ __forceinline__ float dot52(const float* __restrict__ r, const float (&v)[FPAD]) {
    float t0 = 0.f, t1 = 0.f, t2 = 0.f, t3 = 0.f;
    #pragma unroll
    for (int l = 0; l < FPAD; l += 4) {
        t0 = fmaf(r[l + 0], v[l + 0], t0);
        t1 = fmaf(r[l + 1], v[l + 1], t1);
        t2 = fmaf(r[l + 2], v[l + 2], t2);
        t3 = fmaf(r[l + 3], v[l + 3], t3);
    }
    return (t0 + t1) + (t2 + t3);
}

__global__ __launch_bounds__(256) void contract_kernel(const float* __restrict__ x,
                                                       const float* __restrict__ F,
                                                       float* __restrict__ out, int B) {
    const int b = blockIdx.x * 256 + threadIdx.x;
    const int i = blockIdx.y;
    if (b >= B) return;

    float2 xv = ((const float2*)x)[b];
    float s0, c0, s1, c1;
    sincosf(xv.x, &s0, &c0);
    sincosf(xv.y, &s1, &c1);

    float v1[FPAD];
    v1[0] = 1.0f; v1[1] = c1; v1[2] = s1;
    #pragma unroll
    for (int n = 2; n <= 24; ++n) {
        v1[2 * n - 1] = v1[2 * n - 3] * c1 - v1[2 * n - 2] * s1;
        v1[2 * n]     = v1[2 * n - 2] * c1 + v1[2 * n - 3] * s1;
    }
    v1[49] = 0.f; v1[50] = 0.f; v1[51] = 0.f;

    const float* base = F + (size_t)i * NG * FPAD;
    float acc = dot52(base, v1);  // n=0 row
    float Ck = c0, Sk = s0;
    const float* rp = base + FPAD;

    #pragma unroll 2
    for (int n = 1; n <= 24; ++n) {
        float tC = dot52(rp, v1);
        float tS = dot52(rp + FPAD, v1);
        acc = fmaf(Ck, tC, acc);
        acc = fmaf(Sk, tS, acc);
        float Cn = Ck * c0 - Sk * s0;
        float Sn = Sk * c0 + Ck * s0;
        Ck = Cn; Sk = Sn;
        rp += 2 * FPAD;
    }

    const float PI = 3.14159265358979323846f;
    out[(size_t)b * 8 + i] = PI * acc;
}

extern "C" void kernel_launch(void* const* d_in, const int* in_sizes, int n_in,
                              void* d_out, int out_size, void* d_ws, size_t ws_size,
                              hipStream_t stream) {
    (void)n_in; (void)out_size; (void)ws_size;
    const float* x = (const float*)d_in[0];
    const float* w = (const float*)d_in[1];
    float* out = (float*)d_out;
    char* ws = (char*)d_ws;
    float* E  = (float*)(ws + WS_E_OFF);
    float* F  = (float*)(ws + WS_F_OFF);
    const int B = in_sizes[0] / 2;

    hipLaunchKernelGGL(qnn_grid_kernel, dim3((NG2 + 3) / 4), dim3(256), 0, stream, w, E);
    hipLaunchKernelGGL(dft_fused, dim3(8), dim3(256), 0, stream, E, F);
    hipLaunchKernelGGL(contract_kernel, dim3((B + 255) / 256, 8), dim3(256), 0, stream,
                       x, F, out, B);
}